// Round 1
// baseline (558.486 us; speedup 1.0000x reference)
//
#include <hip/hip_runtime.h>

typedef short bfx8 __attribute__((ext_vector_type(8)));
typedef float fx4 __attribute__((ext_vector_type(4)));

#define D 256
#define E_TILE 64

__device__ __forceinline__ float b2f(short s) {
  union { unsigned u; float f; } v; v.u = ((unsigned)(unsigned short)s) << 16; return v.f;
}
__device__ __forceinline__ short f2b(float f) {
  union { float f; unsigned u; } v; v.f = f;
  unsigned u = v.u;
  u += 0x7fffu + ((u >> 16) & 1u);   // RNE
  return (short)(u >> 16);
}
__device__ __forceinline__ float relu(float f) { return f > 0.f ? f : 0.f; }

// ---------------- prep: convert weights to bf16 in ws ----------------
// B1[n][k], n in [0,512): n<256 -> W1[n][k] (P part); n>=256 -> W1[n-256][256+k] (Q part)
__global__ void k_prep(const float* __restrict__ W1, const float* __restrict__ W2,
                       unsigned short* __restrict__ B1, unsigned short* __restrict__ W2b) {
  int t = blockIdx.x * 256 + threadIdx.x;
  if (t < 512 * 256) {
    int n = t >> 8, k = t & 255;
    float v = (n < 256) ? W1[n * 512 + k] : W1[(n - 256) * 512 + 256 + k];
    B1[t] = (unsigned short)f2b(v);
  } else if (t < 512 * 256 + 256 * 256) {
    int i = t - 512 * 256;
    W2b[i] = (unsigned short)f2b(W2[i]);
  }
}

// ---------------- node kernel: PQ[m][0:512] = x[m] @ B1^T (bf16 out) ----------------
// block: 256 thr (4 waves). Tile 64M x 512N, K=256 in 8 chunks of 32.
// wave w owns N range [w*128, w*128+128).
__launch_bounds__(256, 2)
__global__ void k_node(const float* __restrict__ x, const unsigned short* __restrict__ B1,
                       unsigned short* __restrict__ PQ, int n_nodes) {
  __shared__ __align__(16) short smA[64 * 40];    // stride 40 (pad 8) -> 16B aligned rows
  __shared__ __align__(16) short smW[512 * 40];
  short* smT = smW;                               // [32][520] alias for store transpose
  const int tid = threadIdx.x;
  const int wave = tid >> 6, lane = tid & 63;
  const int lr = lane & 15, lg = lane >> 4;
  const int m0 = blockIdx.x * 64;

  fx4 acc[4][8] = {};

#pragma unroll 1
  for (int ks = 0; ks < 8; ++ks) {
    const int k0 = ks * 32;
    // stage A chunk: 64 rows x 32 cols fp32 -> bf16
    {
      int r = tid >> 2, c = (tid & 3) * 8;
      int m = m0 + r;
      bfx8 o;
      if (m < n_nodes) {
        const float* p = x + (size_t)m * 256 + k0 + c;
        float4 v0 = *(const float4*)(p);
        float4 v1 = *(const float4*)(p + 4);
        o[0] = f2b(v0.x); o[1] = f2b(v0.y); o[2] = f2b(v0.z); o[3] = f2b(v0.w);
        o[4] = f2b(v1.x); o[5] = f2b(v1.y); o[6] = f2b(v1.z); o[7] = f2b(v1.w);
      } else {
        o = (bfx8){0,0,0,0,0,0,0,0};
      }
      *(bfx8*)&smA[r * 40 + c] = o;
    }
    // stage W chunk: 512 rows x 32 cols bf16
#pragma unroll
    for (int it = 0; it < 8; ++it) {
      int idx = it * 256 + tid;
      int n = idx >> 2, c = (idx & 3) * 8;
      bfx8 v = *(const bfx8*)(B1 + n * 256 + k0 + c);
      *(bfx8*)&smW[n * 40 + c] = v;
    }
    __syncthreads();
    bfx8 af[4];
#pragma unroll
    for (int mt = 0; mt < 4; ++mt)
      af[mt] = *(const bfx8*)&smA[(mt * 16 + lr) * 40 + lg * 8];
#pragma unroll
    for (int nt = 0; nt < 8; ++nt) {
      int n = wave * 128 + nt * 16 + lr;
      bfx8 bf = *(const bfx8*)&smW[n * 40 + lg * 8];
#pragma unroll
      for (int mt = 0; mt < 4; ++mt)
        acc[mt][nt] = __builtin_amdgcn_mfma_f32_16x16x32_bf16(af[mt], bf, acc[mt][nt], 0, 0, 0);
    }
    __syncthreads();
  }

  // epilogue: two half-passes through smT for coalesced bf16 stores
#pragma unroll 1
  for (int h = 0; h < 2; ++h) {
#pragma unroll
    for (int mt = 2 * h; mt < 2 * h + 2; ++mt)
#pragma unroll
      for (int nt = 0; nt < 8; ++nt)
#pragma unroll
        for (int i = 0; i < 4; ++i) {
          int mrow = mt * 16 + lg * 4 + i - h * 32;
          int n = wave * 128 + nt * 16 + lr;
          smT[mrow * 520 + n] = f2b(acc[mt][nt][i]);
        }
    __syncthreads();
    int r = tid >> 3, cbase = (tid & 7) * 8;
    int m = m0 + h * 32 + r;
    if (m < n_nodes) {
#pragma unroll
      for (int j = 0; j < 8; ++j) {
        int c = cbase + j * 64;
        *(bfx8*)(PQ + (size_t)m * 512 + c) = *(const bfx8*)&smT[r * 520 + c];
      }
    }
    __syncthreads();
  }
}

// ---------------- edge kernel: h1=relu(P[src]+Q[dst]+b1); h2=relu(h1@W2^T+b2); out=h2@w3+b3 --
// persistent, 4 waves/block; wave w owns n in [w*64, w*64+64); W2 frags live in registers.
__launch_bounds__(256, 2)
__global__ void k_edge(const unsigned short* __restrict__ PQ,
                       const int* __restrict__ src, const int* __restrict__ dst,
                       const float* __restrict__ b1, const unsigned short* __restrict__ W2b,
                       const float* __restrict__ b2, const float* __restrict__ W3,
                       const float* __restrict__ b3, float* __restrict__ out,
                       int E, int ntiles) {
  __shared__ __align__(16) short smH[64 * 264];   // stride 264 (pad 8) -> 16B-aligned rows
  __shared__ float smS[4][64];
  __shared__ float smB1[256];
  const int tid = threadIdx.x;
  const int wave = tid >> 6, lane = tid & 63;
  const int lr = lane & 15, lg = lane >> 4;

  if (tid < 256) smB1[tid] = b1[tid];

  // W2 fragments (this wave's 64 N rows, full K=256): 4 n-tiles x 8 k-steps
  bfx8 bw[4][8];
  float b2v[4], w3v[4];
#pragma unroll
  for (int nt = 0; nt < 4; ++nt) {
    int n = wave * 64 + nt * 16 + lr;
    b2v[nt] = b2[n];
    w3v[nt] = W3[n];
#pragma unroll
    for (int ks = 0; ks < 8; ++ks)
      bw[nt][ks] = *(const bfx8*)(W2b + n * 256 + ks * 32 + lg * 8);
  }
  const float b3v = b3[0];
  __syncthreads();

  for (int tile = blockIdx.x; tile < ntiles; tile += gridDim.x) {
    const int base = tile * E_TILE;
    // gather + fuse layer1 (elementwise): h1 = relu(P[src]+Q[dst]+b1) -> smH bf16
    {
      int r = tid >> 2;
      int e = base + r;
      if (e < E) {
        int s = src[e], d = dst[e];
        const unsigned short* ps = PQ + (size_t)s * 512;
        const unsigned short* pd = PQ + (size_t)d * 512 + 256;
#pragma unroll
        for (int it = 0; it < 8; ++it) {
          int c = (tid & 3) * 8 + it * 32;
          bfx8 pv = *(const bfx8*)(ps + c);
          bfx8 qv = *(const bfx8*)(pd + c);
          bfx8 o;
#pragma unroll
          for (int j = 0; j < 8; ++j)
            o[j] = f2b(relu(b2f(pv[j]) + b2f(qv[j]) + smB1[c + j]));
          *(bfx8*)&smH[r * 264 + c] = o;
        }
      } else {
        bfx8 z = (bfx8){0,0,0,0,0,0,0,0};
#pragma unroll
        for (int it = 0; it < 8; ++it) {
          int c = (tid & 3) * 8 + it * 32;
          *(bfx8*)&smH[r * 264 + c] = z;
        }
      }
    }
    __syncthreads();

    // layer2 GEMM: 64M x 64N per wave, K=256
    fx4 acc[4][4] = {};
#pragma unroll
    for (int ks = 0; ks < 8; ++ks) {
      bfx8 af[4];
#pragma unroll
      for (int mt = 0; mt < 4; ++mt)
        af[mt] = *(const bfx8*)&smH[(mt * 16 + lr) * 264 + ks * 32 + lg * 8];
#pragma unroll
      for (int nt = 0; nt < 4; ++nt)
#pragma unroll
        for (int mt = 0; mt < 4; ++mt)
          acc[mt][nt] = __builtin_amdgcn_mfma_f32_16x16x32_bf16(af[mt], bw[nt][ks], acc[mt][nt], 0, 0, 0);
    }

    // epilogue: relu(acc+b2) dot w3, reduce over this wave's 64 n via shfl within 16-groups
#pragma unroll
    for (int mt = 0; mt < 4; ++mt)
#pragma unroll
      for (int i = 0; i < 4; ++i) {
        float p = 0.f;
#pragma unroll
        for (int nt = 0; nt < 4; ++nt)
          p += relu(acc[mt][nt][i] + b2v[nt]) * w3v[nt];
        p += __shfl_xor(p, 1);
        p += __shfl_xor(p, 2);
        p += __shfl_xor(p, 4);
        p += __shfl_xor(p, 8);
        if (lr == 0) smS[wave][mt * 16 + lg * 4 + i] = p;
      }
    __syncthreads();
    if (tid < 64) {
      int e = base + tid;
      if (e < E) out[e] = smS[0][tid] + smS[1][tid] + smS[2][tid] + smS[3][tid] + b3v;
    }
    __syncthreads();
  }
}

// ---------------- fallback (if ws too small): naive fp32, 1 edge per wave ----------------
__global__ void k_fallback(const float* __restrict__ x, const int* __restrict__ src,
                           const int* __restrict__ dst, const float* __restrict__ W1,
                           const float* __restrict__ b1, const float* __restrict__ W2,
                           const float* __restrict__ b2, const float* __restrict__ W3,
                           const float* __restrict__ b3, float* __restrict__ out, int E) {
  __shared__ float smF[4][512];
  __shared__ float smG[4][256];
  int wave = threadIdx.x >> 6, lane = threadIdx.x & 63;
  int e = blockIdx.x * 4 + wave;
  bool valid = e < E;
  int ec = valid ? e : 0;
  int s = src[ec], d = dst[ec];
  for (int j = 0; j < 8; ++j) {
    int k = lane * 8 + j;
    smF[wave][k] = (k < 256) ? x[(size_t)s * 256 + k] : x[(size_t)d * 256 + k - 256];
  }
  __syncthreads();
  for (int t = 0; t < 4; ++t) {
    int n = lane + t * 64;
    float a = b1[n];
    for (int k = 0; k < 512; ++k) a += smF[wave][k] * W1[n * 512 + k];
    smG[wave][n] = relu(a);
  }
  __syncthreads();
  float p = 0.f;
  for (int t = 0; t < 4; ++t) {
    int n = lane + t * 64;
    float a = b2[n];
    for (int k = 0; k < 256; ++k) a += smG[wave][k] * W2[n * 256 + k];
    p += relu(a) * W3[n];
  }
  for (int m = 1; m < 64; m <<= 1) p += __shfl_xor(p, m);
  if (lane == 0 && valid) out[e] = p + b3[0];
}

extern "C" void kernel_launch(void* const* d_in, const int* in_sizes, int n_in,
                              void* d_out, int out_size, void* d_ws, size_t ws_size,
                              hipStream_t stream) {
  const float* x  = (const float*)d_in[0];
  const int*   src = (const int*)d_in[1];
  const int*   dst = (const int*)d_in[2];
  const float* W1 = (const float*)d_in[3];
  const float* b1 = (const float*)d_in[4];
  const float* W2 = (const float*)d_in[5];
  const float* b2 = (const float*)d_in[6];
  const float* W3 = (const float*)d_in[7];
  const float* b3 = (const float*)d_in[8];
  float* out = (float*)d_out;

  const int E = in_sizes[1];
  const int n_nodes = in_sizes[0] / 256;

  const size_t offB1 = 0;
  const size_t offW2 = (size_t)512 * 256 * 2;                 // 262144
  const size_t offPQ = offW2 + (size_t)256 * 256 * 2;         // 393216
  const size_t need = offPQ + (size_t)n_nodes * 512 * 2;      // ~51.6 MB

  if (ws_size >= need) {
    unsigned short* B1  = (unsigned short*)((char*)d_ws + offB1);
    unsigned short* W2b = (unsigned short*)((char*)d_ws + offW2);
    unsigned short* PQ  = (unsigned short*)((char*)d_ws + offPQ);
    k_prep<<<768, 256, 0, stream>>>(W1, W2, B1, W2b);
    k_node<<<(n_nodes + 63) / 64, 256, 0, stream>>>(x, B1, PQ, n_nodes);
    const int ntiles = (E + E_TILE - 1) / E_TILE;
    k_edge<<<512, 256, 0, stream>>>(PQ, src, dst, b1, W2b, b2, W3, b3, out, E, ntiles);
  } else {
    k_fallback<<<(E + 3) / 4, 256, 0, stream>>>(x, src, dst, W1, b1, W2, b2, W3, b3, out, E);
  }
}

// Round 2
// 215.324 us; speedup vs baseline: 2.5937x; 2.5937x over previous
//
#include <hip/hip_runtime.h>

typedef short bfx8 __attribute__((ext_vector_type(8)));
typedef float fx4 __attribute__((ext_vector_type(4)));

#define D 256
#define E_TILE 64

__device__ __forceinline__ float b2f(short s) {
  union { unsigned u; float f; } v; v.u = ((unsigned)(unsigned short)s) << 16; return v.f;
}
__device__ __forceinline__ short f2b(float f) {
  union { float f; unsigned u; } v; v.f = f;
  unsigned u = v.u;
  u += 0x7fffu + ((u >> 16) & 1u);   // RNE
  return (short)(u >> 16);
}
__device__ __forceinline__ float relu(float f) { return f > 0.f ? f : 0.f; }

// ---------------- prep: convert weights to bf16 in ws ----------------
// B1[n][k], n in [0,512): n<256 -> W1[n][k] (P part); n>=256 -> W1[n-256][256+k] (Q part)
__global__ void k_prep(const float* __restrict__ W1, const float* __restrict__ W2,
                       unsigned short* __restrict__ B1, unsigned short* __restrict__ W2b) {
  int t = blockIdx.x * 256 + threadIdx.x;
  if (t < 512 * 256) {
    int n = t >> 8, k = t & 255;
    float v = (n < 256) ? W1[n * 512 + k] : W1[(n - 256) * 512 + 256 + k];
    B1[t] = (unsigned short)f2b(v);
  } else if (t < 512 * 256 + 256 * 256) {
    int i = t - 512 * 256;
    W2b[i] = (unsigned short)f2b(W2[i]);
  }
}

// ---------------- node kernel: PQ[m][0:512] = x[m] @ B1^T (bf16 out) ----------------
// block: 256 thr (4 waves). Tile 64M x 512N, K=256 in 8 chunks of 32.
// wave w owns N range [w*128, w*128+128).
__launch_bounds__(256, 2)
__global__ void k_node(const float* __restrict__ x, const unsigned short* __restrict__ B1,
                       unsigned short* __restrict__ PQ, int n_nodes) {
  __shared__ __align__(16) short smA[64 * 40];    // stride 40 (pad 8) -> 16B aligned rows
  __shared__ __align__(16) short smW[512 * 40];
  short* smT = smW;                               // [32][520] alias for store transpose
  const int tid = threadIdx.x;
  const int wave = tid >> 6, lane = tid & 63;
  const int lr = lane & 15, lg = lane >> 4;
  const int m0 = blockIdx.x * 64;

  fx4 acc[4][8] = {};

#pragma unroll 1
  for (int ks = 0; ks < 8; ++ks) {
    const int k0 = ks * 32;
    // stage A chunk: 64 rows x 32 cols fp32 -> bf16
    {
      int r = tid >> 2, c = (tid & 3) * 8;
      int m = m0 + r;
      bfx8 o;
      if (m < n_nodes) {
        const float* p = x + (size_t)m * 256 + k0 + c;
        float4 v0 = *(const float4*)(p);
        float4 v1 = *(const float4*)(p + 4);
        o[0] = f2b(v0.x); o[1] = f2b(v0.y); o[2] = f2b(v0.z); o[3] = f2b(v0.w);
        o[4] = f2b(v1.x); o[5] = f2b(v1.y); o[6] = f2b(v1.z); o[7] = f2b(v1.w);
      } else {
        o = (bfx8){0,0,0,0,0,0,0,0};
      }
      *(bfx8*)&smA[r * 40 + c] = o;
    }
    // stage W chunk: 512 rows x 32 cols bf16
#pragma unroll
    for (int it = 0; it < 8; ++it) {
      int idx = it * 256 + tid;
      int n = idx >> 2, c = (idx & 3) * 8;
      bfx8 v = *(const bfx8*)(B1 + n * 256 + k0 + c);
      *(bfx8*)&smW[n * 40 + c] = v;
    }
    __syncthreads();
    bfx8 af[4];
#pragma unroll
    for (int mt = 0; mt < 4; ++mt)
      af[mt] = *(const bfx8*)&smA[(mt * 16 + lr) * 40 + lg * 8];
#pragma unroll
    for (int nt = 0; nt < 8; ++nt) {
      int n = wave * 128 + nt * 16 + lr;
      bfx8 bf = *(const bfx8*)&smW[n * 40 + lg * 8];
#pragma unroll
      for (int mt = 0; mt < 4; ++mt)
        acc[mt][nt] = __builtin_amdgcn_mfma_f32_16x16x32_bf16(af[mt], bf, acc[mt][nt], 0, 0, 0);
    }
    __syncthreads();
  }

  // epilogue: two half-passes through smT for coalesced bf16 stores.
  // FULLY unrolled (h compile-time) so acc[] stays statically indexed ->
  // registers, not scratch. (Round-1: `#pragma unroll 1` here made mt
  // runtime-dependent, spilling the 128-float acc to scratch: 1.6 GB of
  // HBM traffic, k_node 385us.)
#pragma unroll
  for (int h = 0; h < 2; ++h) {
#pragma unroll
    for (int mt2 = 0; mt2 < 2; ++mt2) {
      const int mt = 2 * h + mt2;
#pragma unroll
      for (int nt = 0; nt < 8; ++nt)
#pragma unroll
        for (int i = 0; i < 4; ++i) {
          int mrow = mt2 * 16 + lg * 4 + i;
          int n = wave * 128 + nt * 16 + lr;
          smT[mrow * 520 + n] = f2b(acc[mt][nt][i]);
        }
    }
    __syncthreads();
    int r = tid >> 3, cbase = (tid & 7) * 8;
    int m = m0 + h * 32 + r;
    if (m < n_nodes) {
#pragma unroll
      for (int j = 0; j < 8; ++j) {
        int c = cbase + j * 64;
        *(bfx8*)(PQ + (size_t)m * 512 + c) = *(const bfx8*)&smT[r * 520 + c];
      }
    }
    __syncthreads();
  }
}

// ---------------- edge kernel: h1=relu(P[src]+Q[dst]+b1); h2=relu(h1@W2^T+b2); out=h2@w3+b3 --
// persistent, 4 waves/block; wave w owns n in [w*64, w*64+64); W2 frags live in registers.
__launch_bounds__(256, 2)
__global__ void k_edge(const unsigned short* __restrict__ PQ,
                       const int* __restrict__ src, const int* __restrict__ dst,
                       const float* __restrict__ b1, const unsigned short* __restrict__ W2b,
                       const float* __restrict__ b2, const float* __restrict__ W3,
                       const float* __restrict__ b3, float* __restrict__ out,
                       int E, int ntiles) {
  __shared__ __align__(16) short smH[64 * 264];   // stride 264 (pad 8) -> 16B-aligned rows
  __shared__ float smS[4][64];
  __shared__ float smB1[256];
  const int tid = threadIdx.x;
  const int wave = tid >> 6, lane = tid & 63;
  const int lr = lane & 15, lg = lane >> 4;

  if (tid < 256) smB1[tid] = b1[tid];

  // W2 fragments (this wave's 64 N rows, full K=256): 4 n-tiles x 8 k-steps
  bfx8 bw[4][8];
  float b2v[4], w3v[4];
#pragma unroll
  for (int nt = 0; nt < 4; ++nt) {
    int n = wave * 64 + nt * 16 + lr;
    b2v[nt] = b2[n];
    w3v[nt] = W3[n];
#pragma unroll
    for (int ks = 0; ks < 8; ++ks)
      bw[nt][ks] = *(const bfx8*)(W2b + n * 256 + ks * 32 + lg * 8);
  }
  const float b3v = b3[0];
  __syncthreads();

  for (int tile = blockIdx.x; tile < ntiles; tile += gridDim.x) {
    const int base = tile * E_TILE;
    // gather + fuse layer1 (elementwise): h1 = relu(P[src]+Q[dst]+b1) -> smH bf16
    {
      int r = tid >> 2;
      int e = base + r;
      if (e < E) {
        int s = src[e], d = dst[e];
        const unsigned short* ps = PQ + (size_t)s * 512;
        const unsigned short* pd = PQ + (size_t)d * 512 + 256;
#pragma unroll
        for (int it = 0; it < 8; ++it) {
          int c = (tid & 3) * 8 + it * 32;
          bfx8 pv = *(const bfx8*)(ps + c);
          bfx8 qv = *(const bfx8*)(pd + c);
          bfx8 o;
#pragma unroll
          for (int j = 0; j < 8; ++j)
            o[j] = f2b(relu(b2f(pv[j]) + b2f(qv[j]) + smB1[c + j]));
          *(bfx8*)&smH[r * 264 + c] = o;
        }
      } else {
        bfx8 z = (bfx8){0,0,0,0,0,0,0,0};
#pragma unroll
        for (int it = 0; it < 8; ++it) {
          int c = (tid & 3) * 8 + it * 32;
          *(bfx8*)&smH[r * 264 + c] = z;
        }
      }
    }
    __syncthreads();

    // layer2 GEMM: 64M x 64N per wave, K=256
    fx4 acc[4][4] = {};
#pragma unroll
    for (int ks = 0; ks < 8; ++ks) {
      bfx8 af[4];
#pragma unroll
      for (int mt = 0; mt < 4; ++mt)
        af[mt] = *(const bfx8*)&smH[(mt * 16 + lr) * 264 + ks * 32 + lg * 8];
#pragma unroll
      for (int nt = 0; nt < 4; ++nt)
#pragma unroll
        for (int mt = 0; mt < 4; ++mt)
          acc[mt][nt] = __builtin_amdgcn_mfma_f32_16x16x32_bf16(af[mt], bw[nt][ks], acc[mt][nt], 0, 0, 0);
    }

    // epilogue: relu(acc+b2) dot w3, reduce over this wave's 64 n via shfl within 16-groups
#pragma unroll
    for (int mt = 0; mt < 4; ++mt)
#pragma unroll
      for (int i = 0; i < 4; ++i) {
        float p = 0.f;
#pragma unroll
        for (int nt = 0; nt < 4; ++nt)
          p += relu(acc[mt][nt][i] + b2v[nt]) * w3v[nt];
        p += __shfl_xor(p, 1);
        p += __shfl_xor(p, 2);
        p += __shfl_xor(p, 4);
        p += __shfl_xor(p, 8);
        if (lr == 0) smS[wave][mt * 16 + lg * 4 + i] = p;
      }
    __syncthreads();
    if (tid < 64) {
      int e = base + tid;
      if (e < E) out[e] = smS[0][tid] + smS[1][tid] + smS[2][tid] + smS[3][tid] + b3v;
    }
    __syncthreads();
  }
}

// ---------------- fallback (if ws too small): naive fp32, 1 edge per wave ----------------
__global__ void k_fallback(const float* __restrict__ x, const int* __restrict__ src,
                           const int* __restrict__ dst, const float* __restrict__ W1,
                           const float* __restrict__ b1, const float* __restrict__ W2,
                           const float* __restrict__ b2, const float* __restrict__ W3,
                           const float* __restrict__ b3, float* __restrict__ out, int E) {
  __shared__ float smF[4][512];
  __shared__ float smG[4][256];
  int wave = threadIdx.x >> 6, lane = threadIdx.x & 63;
  int e = blockIdx.x * 4 + wave;
  bool valid = e < E;
  int ec = valid ? e : 0;
  int s = src[ec], d = dst[ec];
  for (int j = 0; j < 8; ++j) {
    int k = lane * 8 + j;
    smF[wave][k] = (k < 256) ? x[(size_t)s * 256 + k] : x[(size_t)d * 256 + k - 256];
  }
  __syncthreads();
  for (int t = 0; t < 4; ++t) {
    int n = lane + t * 64;
    float a = b1[n];
    for (int k = 0; k < 512; ++k) a += smF[wave][k] * W1[n * 512 + k];
    smG[wave][n] = relu(a);
  }
  __syncthreads();
  float p = 0.f;
  for (int t = 0; t < 4; ++t) {
    int n = lane + t * 64;
    float a = b2[n];
    for (int k = 0; k < 256; ++k) a += smG[wave][k] * W2[n * 256 + k];
    p += relu(a) * W3[n];
  }
  for (int m = 1; m < 64; m <<= 1) p += __shfl_xor(p, m);
  if (lane == 0 && valid) out[e] = p + b3[0];
}

extern "C" void kernel_launch(void* const* d_in, const int* in_sizes, int n_in,
                              void* d_out, int out_size, void* d_ws, size_t ws_size,
                              hipStream_t stream) {
  const float* x  = (const float*)d_in[0];
  const int*   src = (const int*)d_in[1];
  const int*   dst = (const int*)d_in[2];
  const float* W1 = (const float*)d_in[3];
  const float* b1 = (const float*)d_in[4];
  const float* W2 = (const float*)d_in[5];
  const float* b2 = (const float*)d_in[6];
  const float* W3 = (const float*)d_in[7];
  const float* b3 = (const float*)d_in[8];
  float* out = (float*)d_out;

  const int E = in_sizes[1];
  const int n_nodes = in_sizes[0] / 256;

  const size_t offB1 = 0;
  const size_t offW2 = (size_t)512 * 256 * 2;                 // 262144
  const size_t offPQ = offW2 + (size_t)256 * 256 * 2;         // 393216
  const size_t need = offPQ + (size_t)n_nodes * 512 * 2;      // ~51.6 MB

  if (ws_size >= need) {
    unsigned short* B1  = (unsigned short*)((char*)d_ws + offB1);
    unsigned short* W2b = (unsigned short*)((char*)d_ws + offW2);
    unsigned short* PQ  = (unsigned short*)((char*)d_ws + offPQ);
    k_prep<<<768, 256, 0, stream>>>(W1, W2, B1, W2b);
    k_node<<<(n_nodes + 63) / 64, 256, 0, stream>>>(x, B1, PQ, n_nodes);
    const int ntiles = (E + E_TILE - 1) / E_TILE;
    k_edge<<<512, 256, 0, stream>>>(PQ, src, dst, b1, W2b, b2, W3, b3, out, E, ntiles);
  } else {
    k_fallback<<<(E + 3) / 4, 256, 0, stream>>>(x, src, dst, W1, b1, W2, b2, W3, b3, out, E);
  }
}